// Round 5
// baseline (1817.855 us; speedup 1.0000x reference)
//
#include <hip/hip_runtime.h>

typedef unsigned short u16;
typedef unsigned int   u32;
typedef __bf16 bf16x8 __attribute__((ext_vector_type(8)));
typedef float  f32x4  __attribute__((ext_vector_type(4)));
typedef int    i32x4  __attribute__((ext_vector_type(4)));
typedef unsigned short u16x4 __attribute__((ext_vector_type(4)));

#define Bn 8
#define Sn 96
#define Tn 96
#define Hn 64
#define H2n 128
#define NDIAG 191
#define STR 72   // LDS state row stride in bf16 elems: 144 B -> 16B aligned, 4-bank row stagger

__device__ __forceinline__ float bf2f(u16 u){ return __uint_as_float(((u32)u)<<16); }
__device__ __forceinline__ u16 f2bf_rne(float f){
  u32 u = __float_as_uint(f);
  u += 0x7FFFu + ((u>>16)&1u);
  return (u16)(u>>16);
}
// tanh(x) = (e^{2x}-1)/(e^{2x}+1), clamped so exp never overflows. rel err ~1e-6.
__device__ __forceinline__ float fast_tanh(float x){
  float y = fminf(fmaxf(x+x, -30.f), 30.f);
  float e = __expf(y);
  return (e-1.f)*__builtin_amdgcn_rcpf(e+1.f);
}

// One block per batch sample. 512 threads = 8 waves: wave = (g, nh, mtw2).
//   g    = stream (0: hx-GEMM writes column state sHX; 1: hy-GEMM writes row state sHY)
//   nh   = feature half: this wave computes output features [nh*32, nh*32+32)
//   mtw2 = mtile group: handles mtiles {mtw2, mtw2+2, mtw2+4} of the diagonal
// Weights are hi/lo bf16 split (3-product MFMA: Whi*hhi + Whi*hlo + Wlo*hhi) so the
// whole recurrence is ~fp32-faithful. State and input rows also hi/lo bf16.
// Per diagonal: phase R reads state B-frags (LDS), barrier, phase C MFMAs + tanh
// epilogue + state/global writes, barrier.
__global__ __launch_bounds__(512, 2) void grid_rnn_skew_kernel(
  const float* __restrict__ src, const float* __restrict__ trg,
  const float* __restrict__ Wix, const float* __restrict__ Whx, const float* __restrict__ bx,
  const float* __restrict__ Wiy, const float* __restrict__ Why, const float* __restrict__ by,
  const int* __restrict__ src_lens, const int* __restrict__ trg_lens,
  float* __restrict__ out)
{
  const int b    = blockIdx.x;
  const int tid  = threadIdx.x;
  const int lane = tid & 63;
  const int wid  = tid >> 6;
  const int q    = lane >> 4;   // quad: k-chunk / feature-subrow selector
  const int c    = lane & 15;   // cell-in-tile (B col) / output-feature (A row)
  const int g    = wid >> 2;
  const int nh   = (wid >> 1) & 1;
  const int mtw2 = wid & 1;
  const int sl = src_lens[b], tl = trg_lens[b];

  __shared__ __align__(16) u16 sHXhi[Tn*STR];  // column state: hx(i-1, j), hi part
  __shared__ __align__(16) u16 sHXlo[Tn*STR];
  __shared__ __align__(16) u16 sHYhi[Sn*STR];  // row state: hy(i, j-1), hi part
  __shared__ __align__(16) u16 sHYlo[Sn*STR];

  const float* out0x = out + (size_t)((0*2 + 0)*Bn + b) * (Sn*Tn*Hn); // depth-0 hx
  const float* out0y = out + (size_t)((1*2 + 0)*Bn + b) * (Sn*Tn*Hn); // depth-0 hy

  #pragma unroll
  for (int depth = 0; depth < 2; ++depth){
    // zero recurrence state (borders read zeros)
    for (int idx = tid; idx < (Tn*STR)/2; idx += 512){
      ((u32*)sHXhi)[idx] = 0u; ((u32*)sHXlo)[idx] = 0u;
      ((u32*)sHYhi)[idx] = 0u; ((u32*)sHYlo)[idx] = 0u;
    }

    // ---- weight A-fragments, hi/lo bf16 split (registers, one-time per depth)
    // A[m=c][k=q*8+jj] = W[kbase+q*8+jj][nbase+c];  nbase = nh*32 + v*16
    const float* Wh = (g == 0 ? Whx : Why) + depth*H2n*Hn;
    i32x4 whf_h[2][4], whf_l[2][4];
    #pragma unroll
    for (int v = 0; v < 2; ++v){
      const int nb = nh*32 + v*16 + c;
      #pragma unroll
      for (int kk = 0; kk < 4; ++kk){
        #pragma unroll
        for (int p = 0; p < 4; ++p){
          float w0 = Wh[(kk*32 + q*8 + 2*p    )*Hn + nb];
          float w1 = Wh[(kk*32 + q*8 + 2*p + 1)*Hn + nb];
          u32 h0_ = f2bf_rne(w0), h1_ = f2bf_rne(w1);
          u32 l0_ = f2bf_rne(w0 - bf2f((u16)h0_));
          u32 l1_ = f2bf_rne(w1 - bf2f((u16)h1_));
          whf_h[v][kk][p] = (int)(h0_ | (h1_ << 16));
          whf_l[v][kk][p] = (int)(l0_ | (l1_ << 16));
        }
      }
    }
    const float* Wi = (g == 0 ? Wix : Wiy) + depth*Hn*Hn;
    i32x4 wif_h[2][2], wif_l[2][2];
    #pragma unroll
    for (int v = 0; v < 2; ++v){
      const int nb = nh*32 + v*16 + c;
      #pragma unroll
      for (int kk = 0; kk < 2; ++kk){
        #pragma unroll
        for (int p = 0; p < 4; ++p){
          float w0 = Wi[(kk*32 + q*8 + 2*p    )*Hn + nb];
          float w1 = Wi[(kk*32 + q*8 + 2*p + 1)*Hn + nb];
          u32 h0_ = f2bf_rne(w0), h1_ = f2bf_rne(w1);
          u32 l0_ = f2bf_rne(w0 - bf2f((u16)h0_));
          u32 l1_ = f2bf_rne(w1 - bf2f((u16)h1_));
          wif_h[v][kk][p] = (int)(h0_ | (h1_ << 16));
          wif_l[v][kk][p] = (int)(l0_ | (l1_ << 16));
        }
      }
    }
    // bias -> accumulator init (fp32, exact)
    f32x4 bias4[2];
    const float* bb = (g == 0 ? bx : by) + depth*Hn;
    #pragma unroll
    for (int v = 0; v < 2; ++v)
      #pragma unroll
      for (int r = 0; r < 4; ++r) bias4[v][r] = bb[nh*32 + v*16 + q*4 + r];

    __syncthreads();  // state zeroed + (depth1) depth-0 outputs visible

    for (int d = 0; d < NDIAG; ++d){
      const int i0 = (d > Tn-1) ? d - (Tn-1) : 0;
      const int i1 = (d < Sn-1) ? d : Sn-1;
      const int ncells = i1 - i0 + 1;
      const int mtiles = (ncells + 15) >> 4;

      // ---- phase R: read state B-frags for all assigned mtiles
      i32x4 sf[3][8];
      int iv[3];
      bool act[3];
      #pragma unroll
      for (int u = 0; u < 3; ++u){
        const int mt = mtw2 + 2*u;
        act[u] = (mt < mtiles);
        int cell = mt*16 + c;
        int cc = (cell < ncells) ? cell : ncells - 1;
        iv[u] = i0 + cc;
        if (act[u]){
          const int jr = (d - iv[u])*STR, ir = iv[u]*STR;
          #pragma unroll
          for (int kk = 0; kk < 4; ++kk){
            int off = (kk < 2) ? (jr + kk*32 + q*8) : (ir + (kk-2)*32 + q*8);
            const u16* hbase = (kk < 2) ? sHXhi : sHYhi;
            const u16* lbase = (kk < 2) ? sHXlo : sHYlo;
            sf[u][kk]     = *(const i32x4*)(hbase + off);
            sf[u][4 + kk] = *(const i32x4*)(lbase + off);
          }
        }
      }
      __syncthreads();

      // ---- phase C: MFMAs + tanh epilogue + state/global writes
      #pragma unroll
      for (int u = 0; u < 3; ++u){
        if (!act[u]) continue;
        const int mt = mtw2 + 2*u;
        const int i = iv[u], j = d - i;
        const int cellLin = i*Tn + j;
        const bool valu = (mt*16 + c < ncells);
        // input row (fp32) for the fused projection: depth0 raw src/trg, depth1 out0
        const float* h0;
        if (depth == 0) h0 = (g == 0) ? (src + (b*Sn + i)*Hn) : (trg + (b*Tn + j)*Hn);
        else            h0 = ((g == 0) ? out0x : out0y) + (size_t)cellLin*Hn;
        i32x4 a2h[2], a2l[2];
        #pragma unroll
        for (int s2 = 0; s2 < 2; ++s2){
          const float* p = h0 + s2*32 + q*8;
          f32x4 f0 = *(const f32x4*)(p);
          f32x4 f1 = *(const f32x4*)(p + 4);
          #pragma unroll
          for (int w2 = 0; w2 < 4; ++w2){
            float fa = (w2 < 2) ? f0[2*w2]     : f1[2*(w2-2)];
            float fb = (w2 < 2) ? f0[2*w2 + 1] : f1[2*(w2-2) + 1];
            u16 ha = f2bf_rne(fa), hb_ = f2bf_rne(fb);
            float la = fa - bf2f(ha), lb = fb - bf2f(hb_);
            a2h[s2][w2] = (int)((u32)ha | ((u32)hb_ << 16));
            a2l[s2][w2] = (int)((__float_as_uint(la) >> 16) |
                                ((__float_as_uint(lb) >> 16) << 16));
          }
        }

        float* outg = out + ((size_t)((g*2 + depth)*Bn + b)*(Sn*Tn) + cellLin)*Hn;
        u16* st_hi = (g == 0) ? (sHXhi + j*STR) : (sHYhi + i*STR);
        u16* st_lo = (g == 0) ? (sHXlo + j*STR) : (sHYlo + i*STR);
        const bool mok = (i < sl) && (j < tl);

        #pragma unroll
        for (int v = 0; v < 2; ++v){
          f32x4 acc = bias4[v];
          #pragma unroll
          for (int kk = 0; kk < 4; ++kk){
            acc = __builtin_amdgcn_mfma_f32_16x16x32_bf16(
                    __builtin_bit_cast(bf16x8, whf_h[v][kk]),
                    __builtin_bit_cast(bf16x8, sf[u][kk]), acc, 0, 0, 0);
            acc = __builtin_amdgcn_mfma_f32_16x16x32_bf16(
                    __builtin_bit_cast(bf16x8, whf_h[v][kk]),
                    __builtin_bit_cast(bf16x8, sf[u][4+kk]), acc, 0, 0, 0);
            acc = __builtin_amdgcn_mfma_f32_16x16x32_bf16(
                    __builtin_bit_cast(bf16x8, whf_l[v][kk]),
                    __builtin_bit_cast(bf16x8, sf[u][kk]), acc, 0, 0, 0);
          }
          #pragma unroll
          for (int kk = 0; kk < 2; ++kk){
            acc = __builtin_amdgcn_mfma_f32_16x16x32_bf16(
                    __builtin_bit_cast(bf16x8, wif_h[v][kk]),
                    __builtin_bit_cast(bf16x8, a2h[kk]), acc, 0, 0, 0);
            acc = __builtin_amdgcn_mfma_f32_16x16x32_bf16(
                    __builtin_bit_cast(bf16x8, wif_h[v][kk]),
                    __builtin_bit_cast(bf16x8, a2l[kk]), acc, 0, 0, 0);
            acc = __builtin_amdgcn_mfma_f32_16x16x32_bf16(
                    __builtin_bit_cast(bf16x8, wif_l[v][kk]),
                    __builtin_bit_cast(bf16x8, a2h[kk]), acc, 0, 0, 0);
          }

          // epilogue: lane (q,c) holds features n0..n0+3 of cell c of this mtile
          const int n0 = nh*32 + v*16 + q*4;
          f32x4 hval;
          u16x4 hv, lv;
          #pragma unroll
          for (int r = 0; r < 4; ++r){
            float h  = fast_tanh(acc[r]);
            hval[r]  = h;
            u16 hb   = f2bf_rne(h);
            hv[r]    = hb;
            lv[r]    = (u16)(__float_as_uint(h - bf2f(hb)) >> 16); // truncated lo
          }
          if (valu){
            *(u16x4*)(st_hi + n0) = hv;
            *(u16x4*)(st_lo + n0) = lv;
            f32x4 ov = hval;
            if (depth == 1 && !mok) ov = (f32x4)(0.f);   // depth-1 masked at store
            *(f32x4*)(outg + n0) = ov;                   // depth-0 stored unmasked (fp32)
          }
        }
      }
      __syncthreads();
    }
  }

  // ---- final masking of depth-0 outputs (depth-1 consumed them unmasked above)
  for (int idx = tid; idx < Sn*Tn; idx += 512){
    int i = idx / Tn, j = idx - (idx/Tn)*Tn;
    if (i >= sl || j >= tl){
      float* p0 = out + ((size_t)((0*2+0)*Bn + b)*(Sn*Tn) + idx)*Hn;
      float* p1 = out + ((size_t)((1*2+0)*Bn + b)*(Sn*Tn) + idx)*Hn;
      f32x4 z = (f32x4)(0.f);
      #pragma unroll
      for (int t8 = 0; t8 < 16; ++t8){
        ((f32x4*)p0)[t8] = z;
        ((f32x4*)p1)[t8] = z;
      }
    }
  }
}

extern "C" void kernel_launch(void* const* d_in, const int* in_sizes, int n_in,
                              void* d_out, int out_size, void* d_ws, size_t ws_size,
                              hipStream_t stream) {
  (void)in_sizes; (void)n_in; (void)out_size; (void)d_ws; (void)ws_size;
  grid_rnn_skew_kernel<<<dim3(Bn), dim3(512), 0, stream>>>(
      (const float*)d_in[0], (const float*)d_in[1],
      (const float*)d_in[2], (const float*)d_in[3], (const float*)d_in[4],
      (const float*)d_in[5], (const float*)d_in[6], (const float*)d_in[7],
      (const int*)d_in[8], (const int*)d_in[9],
      (float*)d_out);
}

// Round 6
// 1063.450 us; speedup vs baseline: 1.7094x; 1.7094x over previous
//
#include <hip/hip_runtime.h>

typedef unsigned short u16;
typedef unsigned int   u32;
typedef __bf16 bf16x8 __attribute__((ext_vector_type(8)));
typedef float  f32x4  __attribute__((ext_vector_type(4)));
typedef int    i32x4  __attribute__((ext_vector_type(4)));
typedef unsigned short u16x4 __attribute__((ext_vector_type(4)));

#define Bn 8
#define Sn 96
#define Tn 96
#define Hn 64
#define H2n 128
#define NDIAG 191
#define NROUND 192
#define STR 72            // state row stride (u16): 144B -> 16B aligned, 4-bank row stagger
#define ARR (Sn*STR)      // 6912 u16 per state array; 8 arrays = 110,592 B dynamic LDS

__device__ __forceinline__ float bf2f(u16 u){ return __uint_as_float(((u32)u)<<16); }
__device__ __forceinline__ u16 f2bf_rne(float f){
  u32 u = __float_as_uint(f);
  u += 0x7FFFu + ((u>>16)&1u);
  return (u16)(u>>16);
}
__device__ __forceinline__ float fast_tanh(float x){
  float y = fminf(fmaxf(x+x, -30.f), 30.f);
  float e = __expf(y);
  return (e-1.f)*__builtin_amdgcn_rcpf(e+1.f);
}

// Prologue: depth-0 input projections px[b,g,row,n] (fp32, no bias) into ws.
// Separate kernel => kernel-boundary ordering makes ws visible to the main kernel.
__global__ __launch_bounds__(64) void proj0_kernel(
  const float* __restrict__ src, const float* __restrict__ trg,
  const float* __restrict__ Wix, const float* __restrict__ Wiy,
  float* __restrict__ ws)
{
  const int row = blockIdx.x, g = blockIdx.y, b = blockIdx.z;
  const int n = threadIdx.x;
  const float* x = (g == 0) ? (src + (b*Sn + row)*Hn) : (trg + (b*Tn + row)*Hn);
  const float* W = (g == 0) ? Wix : Wiy;   // depth-0 slice
  float a = 0.f;
  #pragma unroll 8
  for (int f = 0; f < Hn; ++f) a = fmaf(x[f], W[f*Hn + n], a);
  ws[((size_t)(b*2 + g)*Sn + row)*Hn + n] = a;
}

// Fused lag-1 wavefront: round r computes depth-0 diag r AND depth-1 diag r-1.
// 8 waves: wave = (g, nh, dep). dep selects depth; nh the 32-feature half; g the stream.
// Depth-1's input projection operand hx0/hy0(i,j) is read straight from depth-0's
// LDS state slot (written last round, overwritten only in this round's W phase).
// Round = { C: read state + MFMA + tanh (results in regs) ; bar ; W: write state + out ; bar }.
__global__ __launch_bounds__(512, 2) void grid_rnn_fused(
  const float* __restrict__ src, const float* __restrict__ trg,
  const float* __restrict__ Wix, const float* __restrict__ Whx, const float* __restrict__ bx,
  const float* __restrict__ Wiy, const float* __restrict__ Why, const float* __restrict__ by,
  const int* __restrict__ src_lens, const int* __restrict__ trg_lens,
  float* __restrict__ out, const float* __restrict__ ws)
{
  extern __shared__ u16 smem[];
  // layout: [X0hi][X0lo][Y0hi][Y0lo][X1hi][X1lo][Y1hi][Y1lo]
  u16* const sXhi0 = smem;           u16* const sXlo0 = smem + ARR;
  u16* const sYhi0 = smem + 2*ARR;   u16* const sYlo0 = smem + 3*ARR;
  u16* const sXhi1 = smem + 4*ARR;   u16* const sXlo1 = smem + 5*ARR;
  u16* const sYhi1 = smem + 6*ARR;   u16* const sYlo1 = smem + 7*ARR;

  const int b    = blockIdx.x;
  const int tid  = threadIdx.x;
  const int lane = tid & 63;
  const int wid  = tid >> 6;
  const int q    = lane >> 4;
  const int c    = lane & 15;
  const int dep  = wid & 1;
  const int nh   = (wid >> 1) & 1;
  const int g    = wid >> 2;
  const int sl = src_lens[b], tl = trg_lens[b];

  // this wave's recurrence state arrays (its own depth)
  u16* const mXhi = dep ? sXhi1 : sXhi0;  u16* const mXlo = dep ? sXlo1 : sXlo0;
  u16* const mYhi = dep ? sYhi1 : sYhi0;  u16* const mYlo = dep ? sYlo1 : sYlo0;
  // depth-0 state arrays for the depth-1 projection operand (own stream)
  u16* const pHi = (g == 0) ? sXhi0 : sYhi0;
  u16* const pLo = (g == 0) ? sXlo0 : sYlo0;

  // zero all state
  for (int idx = tid; idx < (8*ARR)/2; idx += 512) ((u32*)smem)[idx] = 0u;

  // ---- weights (own depth only), hi/lo bf16 split, A-frag layout
  const float* Wh = (g == 0 ? Whx : Why) + dep*H2n*Hn;
  i32x4 whf_h[2][4], whf_l[2][4];
  #pragma unroll
  for (int v = 0; v < 2; ++v){
    const int nb = nh*32 + v*16 + c;
    #pragma unroll
    for (int kk = 0; kk < 4; ++kk){
      #pragma unroll
      for (int p = 0; p < 4; ++p){
        float w0 = Wh[(kk*32 + q*8 + 2*p    )*Hn + nb];
        float w1 = Wh[(kk*32 + q*8 + 2*p + 1)*Hn + nb];
        u32 h0_ = f2bf_rne(w0), h1_ = f2bf_rne(w1);
        u32 l0_ = f2bf_rne(w0 - bf2f((u16)h0_));
        u32 l1_ = f2bf_rne(w1 - bf2f((u16)h1_));
        whf_h[v][kk][p] = (int)(h0_ | (h1_ << 16));
        whf_l[v][kk][p] = (int)(l0_ | (l1_ << 16));
      }
    }
  }
  // depth-1 input-projection weights (only used by dep==1 waves)
  const float* Wi = (g == 0 ? Wix : Wiy) + Hn*Hn;
  i32x4 wif_h[2][2], wif_l[2][2];
  #pragma unroll
  for (int v = 0; v < 2; ++v){
    const int nb = nh*32 + v*16 + c;
    #pragma unroll
    for (int kk = 0; kk < 2; ++kk){
      #pragma unroll
      for (int p = 0; p < 4; ++p){
        float w0 = Wi[(kk*32 + q*8 + 2*p    )*Hn + nb];
        float w1 = Wi[(kk*32 + q*8 + 2*p + 1)*Hn + nb];
        u32 h0_ = f2bf_rne(w0), h1_ = f2bf_rne(w1);
        u32 l0_ = f2bf_rne(w0 - bf2f((u16)h0_));
        u32 l1_ = f2bf_rne(w1 - bf2f((u16)h1_));
        wif_h[v][kk][p] = (int)(h0_ | (h1_ << 16));
        wif_l[v][kk][p] = (int)(l0_ | (l1_ << 16));
      }
    }
  }
  f32x4 bias4[2];
  const float* bb = (g == 0 ? bx : by) + dep*Hn;
  #pragma unroll
  for (int v = 0; v < 2; ++v)
    #pragma unroll
    for (int r = 0; r < 4; ++r) bias4[v][r] = bb[nh*32 + v*16 + q*4 + r];

  const float* pxbase = ws + (size_t)(b*2 + g)*Sn*Hn;

  __syncthreads();

  for (int r = 0; r < NROUND; ++r){
    const int myd  = r - dep;
    const bool wact = (myd >= 0) && (myd < NDIAG);
    const int i0 = (myd > Tn-1) ? myd - (Tn-1) : 0;
    const int i1 = (myd < Sn-1) ? myd : Sn-1;
    const int nc = i1 - i0 + 1;                 // may be <=0 when inactive
    const int mtiles = (nc + 15) >> 4;

    u16x4 hvv[6][2], lvv[6][2];

    // ---- C phase: read old state, compute; NO state writes
    #pragma unroll
    for (int u = 0; u < 6; ++u){
      const bool act = wact && (u < mtiles);
      if (!act) continue;
      const int cell = u*16 + c;
      const int cc = (cell < nc) ? cell : nc - 1;
      const int i = i0 + cc, j = myd - i;

      f32x4 acc[2];
      #pragma unroll
      for (int v = 0; v < 2; ++v) acc[v] = bias4[v];
      if (dep == 0){
        const float* pxp = pxbase + (size_t)((g == 0) ? i : j)*Hn + nh*32 + q*4;
        #pragma unroll
        for (int v = 0; v < 2; ++v){
          f32x4 px = *(const f32x4*)(pxp + v*16);
          #pragma unroll
          for (int r4 = 0; r4 < 4; ++r4) acc[v][r4] += px[r4];
        }
      }
      // recurrence: K=128 (hx part kk0-1 from col j, hy part kk2-3 from row i)
      #pragma unroll
      for (int kk = 0; kk < 4; ++kk){
        const int off = (kk < 2) ? (j*STR + kk*32 + q*8) : (i*STR + (kk-2)*32 + q*8);
        const u16* hb_ = (kk < 2) ? mXhi : mYhi;
        const u16* lb_ = (kk < 2) ? mXlo : mYlo;
        i32x4 shi = *(const i32x4*)(hb_ + off);
        i32x4 slo = *(const i32x4*)(lb_ + off);
        #pragma unroll
        for (int v = 0; v < 2; ++v){
          acc[v] = __builtin_amdgcn_mfma_f32_16x16x32_bf16(
                     __builtin_bit_cast(bf16x8, whf_h[v][kk]),
                     __builtin_bit_cast(bf16x8, shi), acc[v], 0, 0, 0);
          acc[v] = __builtin_amdgcn_mfma_f32_16x16x32_bf16(
                     __builtin_bit_cast(bf16x8, whf_h[v][kk]),
                     __builtin_bit_cast(bf16x8, slo), acc[v], 0, 0, 0);
          acc[v] = __builtin_amdgcn_mfma_f32_16x16x32_bf16(
                     __builtin_bit_cast(bf16x8, whf_l[v][kk]),
                     __builtin_bit_cast(bf16x8, shi), acc[v], 0, 0, 0);
        }
      }
      // depth-1 projection: operand = depth-0 h at (i,j), straight from LDS state
      if (dep == 1){
        const int pr = ((g == 0) ? j : i)*STR;
        #pragma unroll
        for (int kk = 0; kk < 2; ++kk){
          i32x4 ph = *(const i32x4*)(pHi + pr + kk*32 + q*8);
          i32x4 pl = *(const i32x4*)(pLo + pr + kk*32 + q*8);
          #pragma unroll
          for (int v = 0; v < 2; ++v){
            acc[v] = __builtin_amdgcn_mfma_f32_16x16x32_bf16(
                       __builtin_bit_cast(bf16x8, wif_h[v][kk]),
                       __builtin_bit_cast(bf16x8, ph), acc[v], 0, 0, 0);
            acc[v] = __builtin_amdgcn_mfma_f32_16x16x32_bf16(
                       __builtin_bit_cast(bf16x8, wif_h[v][kk]),
                       __builtin_bit_cast(bf16x8, pl), acc[v], 0, 0, 0);
            acc[v] = __builtin_amdgcn_mfma_f32_16x16x32_bf16(
                       __builtin_bit_cast(bf16x8, wif_l[v][kk]),
                       __builtin_bit_cast(bf16x8, ph), acc[v], 0, 0, 0);
          }
        }
      }
      // tanh epilogue -> packed hi/lo results carried across the barrier
      #pragma unroll
      for (int v = 0; v < 2; ++v){
        #pragma unroll
        for (int r4 = 0; r4 < 4; ++r4){
          float h  = fast_tanh(acc[v][r4]);
          u16 hb2  = f2bf_rne(h);
          hvv[u][v][r4] = hb2;
          lvv[u][v][r4] = (u16)(__float_as_uint(h - bf2f(hb2)) >> 16);
        }
      }
    }
    __syncthreads();

    // ---- W phase: write state + masked global outputs
    #pragma unroll
    for (int u = 0; u < 6; ++u){
      const bool act = wact && (u < mtiles);
      const int cell = u*16 + c;
      if (!act || cell >= nc) continue;
      const int i = i0 + cell, j = myd - i;
      u16* st_hi = (g == 0) ? (mXhi + j*STR) : (mYhi + i*STR);
      u16* st_lo = (g == 0) ? (mXlo + j*STR) : (mYlo + i*STR);
      float* outg = out + ((size_t)((g*2 + dep)*Bn + b)*(Sn*Tn) + i*Tn + j)*Hn;
      const bool mok = (i < sl) && (j < tl);
      #pragma unroll
      for (int v = 0; v < 2; ++v){
        const int n0 = nh*32 + v*16 + q*4;
        *(u16x4*)(st_hi + n0) = hvv[u][v];
        *(u16x4*)(st_lo + n0) = lvv[u][v];
        f32x4 ov;
        #pragma unroll
        for (int r4 = 0; r4 < 4; ++r4){
          float hr = bf2f(hvv[u][v][r4]) + bf2f(lvv[u][v][r4]);
          ov[r4] = mok ? hr : 0.f;
        }
        *(f32x4*)(outg + n0) = ov;
      }
    }
    __syncthreads();
  }
}

extern "C" void kernel_launch(void* const* d_in, const int* in_sizes, int n_in,
                              void* d_out, int out_size, void* d_ws, size_t ws_size,
                              hipStream_t stream) {
  (void)in_sizes; (void)n_in; (void)out_size; (void)ws_size;
  // opt-in to >64KB dynamic LDS (no-op if unnecessary); errors ignored deliberately
  (void)hipFuncSetAttribute((const void*)grid_rnn_fused,
                            hipFuncAttributeMaxDynamicSharedMemorySize, 8*ARR*2);
  proj0_kernel<<<dim3(Sn, 2, Bn), 64, 0, stream>>>(
      (const float*)d_in[0], (const float*)d_in[1],
      (const float*)d_in[2], (const float*)d_in[5],
      (float*)d_ws);
  grid_rnn_fused<<<dim3(Bn), dim3(512), 8*ARR*2, stream>>>(
      (const float*)d_in[0], (const float*)d_in[1],
      (const float*)d_in[2], (const float*)d_in[3], (const float*)d_in[4],
      (const float*)d_in[5], (const float*)d_in[6], (const float*)d_in[7],
      (const int*)d_in[8], (const int*)d_in[9],
      (float*)d_out, (const float*)d_ws);
}

// Round 7
// 1035.284 us; speedup vs baseline: 1.7559x; 1.0272x over previous
//
#include <hip/hip_runtime.h>

typedef unsigned short u16;
typedef unsigned int   u32;
typedef __bf16 bf16x8 __attribute__((ext_vector_type(8)));
typedef float  f32x4  __attribute__((ext_vector_type(4)));
typedef int    i32x4  __attribute__((ext_vector_type(4)));
typedef u32    u32x2  __attribute__((ext_vector_type(2)));

#define Bn 8
#define Sn 96
#define Tn 96
#define Hn 64
#define H2n 128
#define NDIAG 191
#define NROUND 192
#define STR 72            // state row stride (u16): 144B -> 16B aligned, 4-bank row stagger
#define ARR (Sn*STR)      // 6912 u16 per state array; 8 arrays = 110,592 B dynamic LDS

__device__ __forceinline__ float bf2f(u16 u){ return __uint_as_float(((u32)u)<<16); }
__device__ __forceinline__ u16 f2bf_rne(float f){
  u32 u = __float_as_uint(f);
  u += 0x7FFFu + ((u>>16)&1u);
  return (u16)(u>>16);
}
// HW packed fp32->bf16 (RNE): dst = { bf16(b)<<16 | bf16(a) }
__device__ __forceinline__ u32 cvt_pk_bf16(float a, float b){
  u32 r;
  asm("v_cvt_pk_bf16_f32 %0, %1, %2" : "=v"(r) : "v"(a), "v"(b));
  return r;
}
__device__ __forceinline__ float fast_tanh(float x){
  float y = fminf(fmaxf(x+x, -30.f), 30.f);
  float e = __expf(y);
  return (e-1.f)*__builtin_amdgcn_rcpf(e+1.f);
}

// Prologue: depth-0 input projections + bias, px[b,g,row,n] (fp32) into ws.
__global__ __launch_bounds__(64) void proj0_kernel(
  const float* __restrict__ src, const float* __restrict__ trg,
  const float* __restrict__ Wix, const float* __restrict__ Wiy,
  const float* __restrict__ bx, const float* __restrict__ by,
  float* __restrict__ ws)
{
  const int row = blockIdx.x, g = blockIdx.y, b = blockIdx.z;
  const int n = threadIdx.x;
  const float* x = (g == 0) ? (src + (b*Sn + row)*Hn) : (trg + (b*Tn + row)*Hn);
  const float* W = (g == 0) ? Wix : Wiy;   // depth-0 slice
  float a = (g == 0) ? bx[n] : by[n];      // depth-0 bias folded in
  #pragma unroll 8
  for (int f = 0; f < Hn; ++f) a = fmaf(x[f], W[f*Hn + n], a);
  ws[((size_t)(b*2 + g)*Sn + row)*Hn + n] = a;
}

// Fused lag-1 wavefront, 1024 threads = 16 waves: wave = (g, nt, dep).
//   g  = stream (0: hx writes col state sX; 1: hy writes row state sY)
//   nt = 16-feature n-tile [nt*16, nt*16+16)
//   dep= depth; round r: dep0 does diag r, dep1 does diag r-1.
// Depth-1's projection operand hx0/hy0(i,j) comes straight from depth-0's LDS
// state slot (written last round, overwritten only in this round's W phase).
// Round = { C: read state + MFMA + tanh (regs) ; bar ; W: write state + out ; bar }.
__global__ __launch_bounds__(1024, 4) void grid_rnn_fused(
  const float* __restrict__ Whx, const float* __restrict__ Why,
  const float* __restrict__ Wix, const float* __restrict__ Wiy,
  const float* __restrict__ bx,  const float* __restrict__ by,
  const int* __restrict__ src_lens, const int* __restrict__ trg_lens,
  float* __restrict__ out, const float* __restrict__ ws)
{
  extern __shared__ u16 smem[];
  // layout: [X0hi][X0lo][Y0hi][Y0lo][X1hi][X1lo][Y1hi][Y1lo]
  u16* const sXhi0 = smem;           u16* const sXlo0 = smem + ARR;
  u16* const sYhi0 = smem + 2*ARR;   u16* const sYlo0 = smem + 3*ARR;
  u16* const sXhi1 = smem + 4*ARR;   u16* const sXlo1 = smem + 5*ARR;
  u16* const sYhi1 = smem + 6*ARR;   u16* const sYlo1 = smem + 7*ARR;

  const int b    = blockIdx.x;
  const int tid  = threadIdx.x;
  const int lane = tid & 63;
  const int wid  = tid >> 6;
  const int q    = lane >> 4;
  const int c    = lane & 15;
  const int dep  = wid & 1;
  const int nt   = (wid >> 1) & 3;
  const int g    = wid >> 3;
  const int sl = src_lens[b], tl = trg_lens[b];

  u16* const mXhi = dep ? sXhi1 : sXhi0;  u16* const mXlo = dep ? sXlo1 : sXlo0;
  u16* const mYhi = dep ? sYhi1 : sYhi0;  u16* const mYlo = dep ? sYlo1 : sYlo0;
  u16* const pHi = (g == 0) ? sXhi0 : sYhi0;   // depth-0 state for dep1 projection
  u16* const pLo = (g == 0) ? sXlo0 : sYlo0;

  for (int idx = tid; idx < (8*ARR)/2; idx += 1024) ((u32*)smem)[idx] = 0u;

  // ---- weights (own depth, own 16-feature tile), hi/lo bf16 split
  const float* Wh = (g == 0 ? Whx : Why) + dep*H2n*Hn;
  const int nb = nt*16 + c;
  i32x4 whf_h[4], whf_l[4];
  #pragma unroll
  for (int kk = 0; kk < 4; ++kk){
    #pragma unroll
    for (int p = 0; p < 4; ++p){
      float w0 = Wh[(kk*32 + q*8 + 2*p    )*Hn + nb];
      float w1 = Wh[(kk*32 + q*8 + 2*p + 1)*Hn + nb];
      u32 h0_ = f2bf_rne(w0), h1_ = f2bf_rne(w1);
      u32 l0_ = f2bf_rne(w0 - bf2f((u16)h0_));
      u32 l1_ = f2bf_rne(w1 - bf2f((u16)h1_));
      whf_h[kk][p] = (int)(h0_ | (h1_ << 16));
      whf_l[kk][p] = (int)(l0_ | (l1_ << 16));
    }
  }
  const float* Wi = (g == 0 ? Wix : Wiy) + Hn*Hn;  // depth-1 slice (dep1 only)
  i32x4 wif_h[2], wif_l[2];
  #pragma unroll
  for (int kk = 0; kk < 2; ++kk){
    #pragma unroll
    for (int p = 0; p < 4; ++p){
      float w0 = Wi[(kk*32 + q*8 + 2*p    )*Hn + nb];
      float w1 = Wi[(kk*32 + q*8 + 2*p + 1)*Hn + nb];
      u32 h0_ = f2bf_rne(w0), h1_ = f2bf_rne(w1);
      u32 l0_ = f2bf_rne(w0 - bf2f((u16)h0_));
      u32 l1_ = f2bf_rne(w1 - bf2f((u16)h1_));
      wif_h[kk][p] = (int)(h0_ | (h1_ << 16));
      wif_l[kk][p] = (int)(l0_ | (l1_ << 16));
    }
  }
  f32x4 bias4;  // depth-1 bias (dep0 gets bias via ws projections)
  {
    const float* bb = (g == 0 ? bx : by) + dep*Hn;
    #pragma unroll
    for (int r = 0; r < 4; ++r) bias4[r] = bb[nt*16 + q*4 + r];
  }
  const float* pxbase = ws + (size_t)(b*2 + g)*Sn*Hn;

  __syncthreads();

  for (int r = 0; r < NROUND; ++r){
    const int myd  = r - dep;
    const bool wact = (myd >= 0) && (myd < NDIAG);
    const int i0 = (myd > Tn-1) ? myd - (Tn-1) : 0;
    const int i1 = (myd < Sn-1) ? myd : Sn-1;
    const int nc = i1 - i0 + 1;
    const int mtiles = (nc + 15) >> 4;

    u32x2 hvp[6], lvp[6];   // packed hi/lo results carried across the barrier

    // ---- C phase: read old state, compute; NO state writes
    #pragma unroll
    for (int u = 0; u < 6; ++u){
      const bool act = wact && (u < mtiles);
      if (!act) continue;
      const int cell = u*16 + c;
      const int cc = (cell < nc) ? cell : nc - 1;
      const int i = i0 + cc, j = myd - i;

      f32x4 acc;
      if (dep == 0){
        acc = *(const f32x4*)(pxbase + (size_t)((g == 0) ? i : j)*Hn + nt*16 + q*4);
      } else {
        acc = bias4;
      }
      // recurrence: K=128 (kk0-1: hx from col j; kk2-3: hy from row i)
      #pragma unroll
      for (int kk = 0; kk < 4; ++kk){
        const int off = (kk < 2) ? (j*STR + kk*32 + q*8) : (i*STR + (kk-2)*32 + q*8);
        const u16* hb_ = (kk < 2) ? mXhi : mYhi;
        const u16* lb_ = (kk < 2) ? mXlo : mYlo;
        i32x4 shi = *(const i32x4*)(hb_ + off);
        i32x4 slo = *(const i32x4*)(lb_ + off);
        acc = __builtin_amdgcn_mfma_f32_16x16x32_bf16(
                __builtin_bit_cast(bf16x8, whf_h[kk]),
                __builtin_bit_cast(bf16x8, shi), acc, 0, 0, 0);
        acc = __builtin_amdgcn_mfma_f32_16x16x32_bf16(
                __builtin_bit_cast(bf16x8, whf_h[kk]),
                __builtin_bit_cast(bf16x8, slo), acc, 0, 0, 0);
        acc = __builtin_amdgcn_mfma_f32_16x16x32_bf16(
                __builtin_bit_cast(bf16x8, whf_l[kk]),
                __builtin_bit_cast(bf16x8, shi), acc, 0, 0, 0);
      }
      // depth-1 projection: operand = depth-0 h at (i,j) straight from LDS
      if (dep == 1){
        const int pr = ((g == 0) ? j : i)*STR;
        #pragma unroll
        for (int kk = 0; kk < 2; ++kk){
          i32x4 ph = *(const i32x4*)(pHi + pr + kk*32 + q*8);
          i32x4 pl = *(const i32x4*)(pLo + pr + kk*32 + q*8);
          acc = __builtin_amdgcn_mfma_f32_16x16x32_bf16(
                  __builtin_bit_cast(bf16x8, wif_h[kk]),
                  __builtin_bit_cast(bf16x8, ph), acc, 0, 0, 0);
          acc = __builtin_amdgcn_mfma_f32_16x16x32_bf16(
                  __builtin_bit_cast(bf16x8, wif_h[kk]),
                  __builtin_bit_cast(bf16x8, pl), acc, 0, 0, 0);
          acc = __builtin_amdgcn_mfma_f32_16x16x32_bf16(
                  __builtin_bit_cast(bf16x8, wif_l[kk]),
                  __builtin_bit_cast(bf16x8, pl), acc, 0, 0, 0);
        }
      }
      // tanh -> HW packed hi/lo split (RNE both levels)
      float h0 = fast_tanh(acc[0]), h1 = fast_tanh(acc[1]);
      float h2 = fast_tanh(acc[2]), h3 = fast_tanh(acc[3]);
      u32 hv01 = cvt_pk_bf16(h0, h1);
      u32 hv23 = cvt_pk_bf16(h2, h3);
      float l0 = h0 - __uint_as_float(hv01 << 16);
      float l1 = h1 - __uint_as_float(hv01 & 0xFFFF0000u);
      float l2 = h2 - __uint_as_float(hv23 << 16);
      float l3 = h3 - __uint_as_float(hv23 & 0xFFFF0000u);
      hvp[u][0] = hv01; hvp[u][1] = hv23;
      lvp[u][0] = cvt_pk_bf16(l0, l1);
      lvp[u][1] = cvt_pk_bf16(l2, l3);
    }
    __syncthreads();

    // ---- W phase: write state + masked global outputs
    #pragma unroll
    for (int u = 0; u < 6; ++u){
      const bool act = wact && (u < mtiles);
      const int cell = u*16 + c;
      if (!act || cell >= nc) continue;
      const int i = i0 + cell, j = myd - i;
      const int n0 = nt*16 + q*4;
      u16* st_hi = ((g == 0) ? (mXhi + j*STR) : (mYhi + i*STR)) + n0;
      u16* st_lo = ((g == 0) ? (mXlo + j*STR) : (mYlo + i*STR)) + n0;
      *(u32x2*)st_hi = hvp[u];
      *(u32x2*)st_lo = lvp[u];
      const bool mok = (i < sl) && (j < tl);
      f32x4 ov;
      ov[0] = __uint_as_float(hvp[u][0] << 16)          + __uint_as_float(lvp[u][0] << 16);
      ov[1] = __uint_as_float(hvp[u][0] & 0xFFFF0000u)  + __uint_as_float(lvp[u][0] & 0xFFFF0000u);
      ov[2] = __uint_as_float(hvp[u][1] << 16)          + __uint_as_float(lvp[u][1] << 16);
      ov[3] = __uint_as_float(hvp[u][1] & 0xFFFF0000u)  + __uint_as_float(lvp[u][1] & 0xFFFF0000u);
      if (!mok) ov = (f32x4)(0.f);
      float* outg = out + ((size_t)((g*2 + dep)*Bn + b)*(Sn*Tn) + i*Tn + j)*Hn + n0;
      *(f32x4*)outg = ov;
    }
    __syncthreads();
  }
}

extern "C" void kernel_launch(void* const* d_in, const int* in_sizes, int n_in,
                              void* d_out, int out_size, void* d_ws, size_t ws_size,
                              hipStream_t stream) {
  (void)in_sizes; (void)n_in; (void)out_size; (void)ws_size;
  (void)hipFuncSetAttribute((const void*)grid_rnn_fused,
                            hipFuncAttributeMaxDynamicSharedMemorySize, 8*ARR*2);
  proj0_kernel<<<dim3(Sn, 2, Bn), 64, 0, stream>>>(
      (const float*)d_in[0], (const float*)d_in[1],
      (const float*)d_in[2], (const float*)d_in[5],
      (const float*)d_in[4], (const float*)d_in[7],
      (float*)d_ws);
  grid_rnn_fused<<<dim3(Bn), dim3(1024), 8*ARR*2, stream>>>(
      (const float*)d_in[3], (const float*)d_in[6],
      (const float*)d_in[2], (const float*)d_in[5],
      (const float*)d_in[4], (const float*)d_in[7],
      (const int*)d_in[8], (const int*)d_in[9],
      (float*)d_out, (const float*)d_ws);
}